// Round 2
// baseline (10999.809 us; speedup 1.0000x reference)
//
#include <hip/hip_runtime.h>
#include <math.h>

constexpr int B_   = 64;
constexpr int T_   = 512;
constexpr int D_   = 512;
constexpr int H_   = 1024;
constexpr int IMG_ = 2048;
constexpr int NWG  = 256;
constexpr int NTHR = 256;
constexpr int GRP  = 128;       // WGs per rgid-barrier (two independent halves)
constexpr int KTOT = D_ + H_;   // 1536

typedef __attribute__((ext_vector_type(8)))  short          short8;
typedef __attribute__((ext_vector_type(16))) float          f32x16;
typedef __attribute__((ext_vector_type(4)))  unsigned short ushort4v;

__device__ __forceinline__ unsigned short f2bf(float f) {
  unsigned u = __float_as_uint(f);
  u += 0x7FFFu + ((u >> 16) & 1u);     // round-to-nearest-even
  return (unsigned short)(u >> 16);
}

__device__ __forceinline__ float sigf(float v) {
  return 1.0f / (1.0f + __expf(-v));
}

// Persistent multimodal-LSTM kernel, hand-rolled agent-scope coherence:
// h-exchange via relaxed agent atomics (sc0sc1 write-through / coherent loads),
// vmcnt(0)+barrier release ordering, NO threadfence (L2 stays warm).
// Grid: 256 WGs x 256 threads, 1 WG/CU. Two independent 128-WG barriers (per rgid).
// WG (rg, cg): batch rows [rg*32, rg*32+32), h-cols [cg*8, cg*8+8) (x4 gates).
__global__ void __launch_bounds__(NTHR, 1)
mmlstm_persistent(const float* __restrict__ x,
                  const float* __restrict__ img,
                  const float* __restrict__ W_ih,
                  const float* __restrict__ W_hh,
                  const float* __restrict__ b_ih,
                  const float* __restrict__ b_hh,
                  const float* __restrict__ W_m,
                  float* __restrict__ out,
                  float* __restrict__ hn,
                  float* __restrict__ cn,
                  unsigned* __restrict__ bar,
                  unsigned* __restrict__ Ah0,
                  unsigned* __restrict__ Ah1)
{
  __shared__ unsigned short Wlds[32 * KTOT];   // 96 KiB: 32 gate rows x 1536 K, bf16, swizzled
  __shared__ unsigned short Axlds[32 * 512];   // 32 KiB: A-panel chunk (32 rows x K=512), swizzled
  __shared__ float gaccs[4][32][33];           // 16.5 KiB: per-wave partial gate accs
  __shared__ float bias_lds[32];

  const int tid  = threadIdx.x;
  const int lane = tid & 63;
  const int wv   = tid >> 6;
  const int wg   = blockIdx.x;
  const int rgid = wg & 1;
  const int cgid = wg >> 1;
  const int brow0 = rgid * 32;
  const int j0    = cgid * 8;

  unsigned* mybar = bar + rgid * 32;   // 128 B apart -> separate cachelines

  // ---- stage W slice (32 gate rows = 4 gates x 8 h-cols) into LDS, bf16, XOR-swizzled ----
  for (int c = 0; c < 32; ++c) {
    const int grow = (c >> 3) * H_ + j0 + (c & 7);
    const int sw   = (c & 15) << 3;
    for (int k = tid; k < KTOT; k += NTHR) {
      const float w = (k < D_) ? W_ih[(size_t)grow * D_ + k]
                               : W_hh[(size_t)grow * H_ + (k - D_)];
      Wlds[c * KTOT + (k ^ sw)] = f2bf(w);
    }
  }
  if (tid < 32) {
    const int grow = (tid >> 3) * H_ + j0 + (tid & 7);
    bias_lds[tid] = b_ih[grow] + b_hh[grow];
  }

  // ---- per-thread ownership: thread = (b_l, jj) -> (b, j); c-state in a VGPR ----
  const int b_l = tid >> 3;
  const int jj  = tid & 7;
  const int b   = brow0 + b_l;
  const int j   = j0 + jj;

  // multimodal gate d[b][j] = img[b] . W_m[j]  (fp32, one dot per thread)
  float dval = 0.0f;
  {
    const float4* ir = (const float4*)(img + (size_t)b * IMG_);
    const float4* wr = (const float4*)(W_m + (size_t)j * IMG_);
    for (int k = 0; k < IMG_ / 4; ++k) {
      const float4 a = ir[k];
      const float4 w = wr[k];
      dval += a.x * w.x + a.y * w.y + a.z * w.z + a.w * w.w;
    }
  }

  // h0 * d = 0 : publish zeros via coherent stores (even-jj threads, packed u32)
  if ((tid & 1) == 0)
    __hip_atomic_store(Ah0 + (size_t)b * (H_ / 2) + (j >> 1), 0u,
                       __ATOMIC_RELAXED, __HIP_MEMORY_SCOPE_AGENT);

  float  cstate = 0.0f;
  f32x16 acc    = {};

  asm volatile("s_waitcnt vmcnt(0)" ::: "memory");
  __syncthreads();   // all waves' publishes drained; Wlds/bias ready

  if (tid == 0)
    __hip_atomic_fetch_add(mybar, 1u, __ATOMIC_RELAXED, __HIP_MEMORY_SCOPE_AGENT);

  unsigned* Acur  = Ah0;
  unsigned* Anext = Ah1;
  unsigned wait_target = GRP;

  // X-projection phase for step t: independent of h -> hides barrier latency.
  auto xphase = [&](int t) {
    for (int i = 0; i < 16; ++i) {
      const int idx = i * NTHR + tid;
      const int r   = idx >> 7;          // 128 float4 per row
      const int pos = idx & 127;
      const float4 v = *(const float4*)(x + ((size_t)(brow0 + r) * T_ + t) * D_ + pos * 4);
      ushort4v pk;
      pk.x = f2bf(v.x); pk.y = f2bf(v.y); pk.z = f2bf(v.z); pk.w = f2bf(v.w);
      *(ushort4v*)(Axlds + r * 512 + ((pos * 4) ^ ((r & 15) << 3))) = pk;
    }
    __syncthreads();
    acc = {};
    const int r  = lane & 31;            // doubles as A row and B (gate) col
    const int kh = (lane >> 5) << 3;
    #pragma unroll
    for (int s8 = 0; s8 < 8; ++s8) {     // K-steps s = wv, wv+4, ..., wv+28 (mod-4 split)
      const int kl = (wv + s8 * 4) * 16 + kh;
      const short8 af = *(const short8*)(Axlds + r * 512  + (kl ^ ((r & 15) << 3)));
      const short8 bf = *(const short8*)(Wlds  + r * KTOT + (kl ^ ((r & 15) << 3)));
      acc = __builtin_amdgcn_mfma_f32_32x32x16_bf16(af, bf, acc, 0, 0, 0);
    }
  };

  xphase(0);

  for (int t = 0; t < T_; ++t) {
    // ---- wait for h_t (published by the 128 WGs of this rgid) ----
    if (tid == 0) {
      while (__hip_atomic_load(mybar, __ATOMIC_RELAXED, __HIP_MEMORY_SCOPE_AGENT) < wait_target)
        __builtin_amdgcn_s_sleep(1);
    }
    __syncthreads();
    wait_target += GRP;

    // ---- recurrent part: two K=512 chunks of (h*d), coherent u32 loads ----
    #pragma unroll
    for (int hc = 0; hc < 2; ++hc) {
      for (int i = 0; i < 32; ++i) {
        const int idx = i * NTHR + tid;
        const int r   = idx >> 8;        // 256 u32 per row-chunk
        const int pu  = idx & 255;
        const unsigned v = __hip_atomic_load(
            Acur + (size_t)(brow0 + r) * (H_ / 2) + hc * 256 + pu,
            __ATOMIC_RELAXED, __HIP_MEMORY_SCOPE_AGENT);
        *(unsigned*)(Axlds + (r * 512 + ((pu * 2) ^ ((r & 15) << 3)))) = v;
      }
      __syncthreads();
      {
        const int r  = lane & 31;
        const int kh = (lane >> 5) << 3;
        #pragma unroll
        for (int s8 = 0; s8 < 8; ++s8) {
          const int kloc = (wv + s8 * 4) * 16 + kh;
          const int kglb = D_ + hc * 512 + kloc;
          const short8 af = *(const short8*)(Axlds + r * 512  + (kloc ^ ((r & 15) << 3)));
          const short8 bf = *(const short8*)(Wlds  + r * KTOT + (kglb ^ ((r & 15) << 3)));
          acc = __builtin_amdgcn_mfma_f32_32x32x16_bf16(af, bf, acc, 0, 0, 0);
        }
      }
      __syncthreads();   // before next chunk overwrites Axlds
    }

    // ---- per-wave partials (C/D layout: col=lane&31, row=(r&3)+8*(r>>2)+4*(lane>>5)) ----
    {
      const int colw  = lane & 31;
      const int rbase = (lane >> 5) * 4;
      #pragma unroll
      for (int rr = 0; rr < 16; ++rr) {
        const int row = (rr & 3) + 8 * (rr >> 2) + rbase;
        gaccs[wv][row][colw] = acc[rr];
      }
    }
    __syncthreads();

    // ---- cell update: thread owns (b, j) ----
    float gv[4];
    #pragma unroll
    for (int g = 0; g < 4; ++g) {
      const int c = g * 8 + jj;
      gv[g] = gaccs[0][b_l][c] + gaccs[1][b_l][c] + gaccs[2][b_l][c] + gaccs[3][b_l][c]
            + bias_lds[c];
    }
    const float ig = sigf(gv[0]);
    const float fg = sigf(gv[1]);
    const float gg = tanhf(gv[2]);
    const float og = sigf(gv[3]);
    cstate = fg * cstate + ig * gg;
    const float h = og * tanhf(cstate);
    __builtin_nontemporal_store(h, &out[((size_t)b * T_ + t) * H_ + j]);

    // publish h*d packed as u32 (even jj stores {j, j+1}) via coherent store
    {
      const unsigned hd  = f2bf(h * dval);
      const unsigned nxt = __shfl_down((int)hd, 1);
      if ((jj & 1) == 0)
        __hip_atomic_store(Anext + (size_t)b * (H_ / 2) + (j >> 1),
                           hd | (nxt << 16),
                           __ATOMIC_RELAXED, __HIP_MEMORY_SCOPE_AGENT);
    }
    if (t == T_ - 1) {
      hn[(size_t)b * H_ + j] = h;
      cn[(size_t)b * H_ + j] = cstate;
    }

    asm volatile("s_waitcnt vmcnt(0)" ::: "memory");  // publishes at coherent point
    __syncthreads();                                  // every wave drained

    if (t < T_ - 1) {
      if (tid == 0)
        __hip_atomic_fetch_add(mybar, 1u, __ATOMIC_RELAXED, __HIP_MEMORY_SCOPE_AGENT);
      xphase(t + 1);      // h-independent work hides barrier latency
    }
    unsigned* tmp = Acur; Acur = Anext; Anext = tmp;
  }
}

extern "C" void kernel_launch(void* const* d_in, const int* in_sizes, int n_in,
                              void* d_out, int out_size, void* d_ws, size_t ws_size,
                              hipStream_t stream) {
  (void)in_sizes; (void)n_in; (void)out_size; (void)ws_size;
  const float* x    = (const float*)d_in[0];
  const float* img  = (const float*)d_in[1];
  const float* W_ih = (const float*)d_in[2];
  const float* W_hh = (const float*)d_in[3];
  const float* b_ih = (const float*)d_in[4];
  const float* b_hh = (const float*)d_in[5];
  const float* W_m  = (const float*)d_in[6];

  float* out = (float*)d_out;
  float* hn  = out + (size_t)B_ * T_ * H_;
  float* cn  = hn + (size_t)B_ * H_;

  unsigned* bar = (unsigned*)d_ws;
  unsigned* Ah0 = (unsigned*)((char*)d_ws + 256);
  unsigned* Ah1 = (unsigned*)((char*)d_ws + 256 + (size_t)B_ * H_ * 2);

  hipMemsetAsync(d_ws, 0, 256, stream);   // reset both barrier counters each call
  hipLaunchKernelGGL(mmlstm_persistent, dim3(NWG), dim3(NTHR), 0, stream,
                     x, img, W_ih, W_hh, b_ih, b_hh, W_m, out, hn, cn, bar, Ah0, Ah1);
}

// Round 3
// 2537.798 us; speedup vs baseline: 4.3344x; 4.3344x over previous
//
#include <hip/hip_runtime.h>
#include <math.h>

constexpr int B_   = 64;
constexpr int T_   = 512;
constexpr int D_   = 512;
constexpr int H_   = 1024;
constexpr int IMG_ = 2048;
constexpr int NWG  = 256;
constexpr int NTHR = 256;
constexpr int GRP  = 128;       // WGs per rgid-barrier (two independent halves)
constexpr int KTOT = D_ + H_;   // 1536

typedef __attribute__((ext_vector_type(8)))  short          short8;
typedef __attribute__((ext_vector_type(16))) float          f32x16;
typedef __attribute__((ext_vector_type(4)))  unsigned short ushort4v;
typedef __attribute__((ext_vector_type(4)))  unsigned       uint4v;

__device__ __forceinline__ unsigned short f2bf(float f) {
  unsigned u = __float_as_uint(f);
  u += 0x7FFFu + ((u >> 16) & 1u);     // round-to-nearest-even
  return (unsigned short)(u >> 16);
}

__device__ __forceinline__ float sigf(float v) {
  return 1.0f / (1.0f + __expf(-v));
}

// Persistent multimodal-LSTM. Fence-free agent-scope coherence (validated R2):
// publishes via relaxed-atomic u32 stores (sc0 sc1 write-through to coherent L3),
// consumer panel reads via inline-asm global_load_dwordx4 sc0 sc1 (coalesced,
// L1/L2-bypass -> always coherent), release = s_waitcnt vmcnt(0) + __syncthreads
// before the arrive-atomic. No threadfence -> L2 stays warm for x/W streams.
// Grid: 256 WGs x 256 thr, 1 WG/CU (LDS-bound). Two independent 128-WG barriers.
__global__ void __launch_bounds__(NTHR, 1)
mmlstm_persistent(const float* __restrict__ x,
                  const float* __restrict__ img,
                  const float* __restrict__ W_ih,
                  const float* __restrict__ W_hh,
                  const float* __restrict__ b_ih,
                  const float* __restrict__ b_hh,
                  const float* __restrict__ W_m,
                  float* __restrict__ out,
                  float* __restrict__ hn,
                  float* __restrict__ cn,
                  unsigned* __restrict__ bar,
                  unsigned* __restrict__ Ah0,
                  unsigned* __restrict__ Ah1)
{
  __shared__ unsigned short Wlds[32 * KTOT];   // 96 KiB: 32 gate rows x 1536 K, bf16, swizzled
  __shared__ unsigned short Axlds[32 * 512];   // 32 KiB: A-panel chunk (32 rows x K=512), swizzled
  __shared__ float gaccs[4][32][33];           // per-wave partial gate accs
  __shared__ float bias_lds[32];

  const int tid  = threadIdx.x;
  const int lane = tid & 63;
  const int wv   = tid >> 6;
  const int wg   = blockIdx.x;
  const int rgid = wg & 1;
  const int cgid = wg >> 1;
  const int brow0 = rgid * 32;
  const int j0    = cgid * 8;

  unsigned* mybar = bar + rgid * 32;   // separate cachelines per half

  // ---- stage W slice (32 gate rows = 4 gates x 8 h-cols) into LDS, bf16, XOR-swizzled ----
  for (int c = 0; c < 32; ++c) {
    const int grow = (c >> 3) * H_ + j0 + (c & 7);
    const int sw   = (c & 15) << 3;
    for (int k = tid; k < KTOT; k += NTHR) {
      const float w = (k < D_) ? W_ih[(size_t)grow * D_ + k]
                               : W_hh[(size_t)grow * H_ + (k - D_)];
      Wlds[c * KTOT + (k ^ sw)] = f2bf(w);
    }
  }
  if (tid < 32) {
    const int grow = (tid >> 3) * H_ + j0 + (tid & 7);
    bias_lds[tid] = b_ih[grow] + b_hh[grow];
  }

  // ---- per-thread ownership: thread = (b_l, jj) -> (b, j); c-state in a VGPR ----
  const int b_l = tid >> 3;
  const int jj  = tid & 7;
  const int b   = brow0 + b_l;
  const int j   = j0 + jj;

  // multimodal gate d[b][j] = img[b] . W_m[j]  (fp32, one dot per thread)
  float dval = 0.0f;
  {
    const float4* ir = (const float4*)(img + (size_t)b * IMG_);
    const float4* wr = (const float4*)(W_m + (size_t)j * IMG_);
    for (int k = 0; k < IMG_ / 4; ++k) {
      const float4 a = ir[k];
      const float4 w = wr[k];
      dval += a.x * w.x + a.y * w.y + a.z * w.z + a.w * w.w;
    }
  }

  // h0 * d = 0 : publish zeros via coherent stores (even-jj threads, packed u32)
  if ((tid & 1) == 0)
    __hip_atomic_store(Ah0 + (size_t)b * (H_ / 2) + (j >> 1), 0u,
                       __ATOMIC_RELAXED, __HIP_MEMORY_SCOPE_AGENT);

  float  cstate = 0.0f;
  f32x16 acc    = {};

  asm volatile("s_waitcnt vmcnt(0)" ::: "memory");
  __syncthreads();   // all publishes drained; Wlds/bias ready

  if (tid == 0)
    __hip_atomic_fetch_add(mybar, 1u, __ATOMIC_RELAXED, __HIP_MEMORY_SCOPE_AGENT);

  unsigned* Acur  = Ah0;
  unsigned* Anext = Ah1;
  unsigned wait_target = GRP;

  float4 xr[16];

  auto xload = [&](int t) {   // issue x loads for step t (h-independent)
    #pragma unroll
    for (int i = 0; i < 16; ++i) {
      const int idx = i * NTHR + tid;
      const int r   = idx >> 7;          // 128 float4 per row
      const int pos = idx & 127;
      xr[i] = *(const float4*)(x + ((size_t)(brow0 + r) * T_ + t) * D_ + pos * 4);
    }
  };

  auto xfin = [&]() {          // convert + stage + x-projection MFMA (acc init)
    #pragma unroll
    for (int i = 0; i < 16; ++i) {
      const int idx = i * NTHR + tid;
      const int r   = idx >> 7;
      const int pos = idx & 127;
      ushort4v pk;
      pk.x = f2bf(xr[i].x); pk.y = f2bf(xr[i].y);
      pk.z = f2bf(xr[i].z); pk.w = f2bf(xr[i].w);
      *(ushort4v*)(Axlds + r * 512 + ((pos * 4) ^ ((r & 15) << 3))) = pk;
    }
    __syncthreads();
    acc = {};
    const int r  = lane & 31;
    const int kh = (lane >> 5) << 3;
    #pragma unroll
    for (int s8 = 0; s8 < 8; ++s8) {
      const int kl = (wv + s8 * 4) * 16 + kh;
      const short8 af = *(const short8*)(Axlds + r * 512  + (kl ^ ((r & 15) << 3)));
      const short8 bf = *(const short8*)(Wlds  + r * KTOT + (kl ^ ((r & 15) << 3)));
      acc = __builtin_amdgcn_mfma_f32_32x32x16_bf16(af, bf, acc, 0, 0, 0);
    }
  };

  auto hmfma = [&](int hc) {   // recurrent MFMA over the staged h-chunk
    const int r  = lane & 31;
    const int kh = (lane >> 5) << 3;
    #pragma unroll
    for (int s8 = 0; s8 < 8; ++s8) {
      const int kloc = (wv + s8 * 4) * 16 + kh;
      const int kglb = D_ + hc * 512 + kloc;
      const short8 af = *(const short8*)(Axlds + r * 512  + (kloc ^ ((r & 15) << 3)));
      const short8 bf = *(const short8*)(Wlds  + r * KTOT + (kglb ^ ((r & 15) << 3)));
      acc = __builtin_amdgcn_mfma_f32_32x32x16_bf16(af, bf, acc, 0, 0, 0);
    }
  };

  xload(0);
  xfin();

  for (int t = 0; t < T_; ++t) {
    // ---- wait for h_t (published by the 128 WGs of this rgid) ----
    if (tid == 0) {
      while (__hip_atomic_load(mybar, __ATOMIC_RELAXED, __HIP_MEMORY_SCOPE_AGENT) < wait_target)
        __builtin_amdgcn_s_sleep(1);
    }
    __syncthreads();   // also guarantees all waves finished reading Axlds (x-tile)
    wait_target += GRP;

    // ---- recurrent part: two K=512 chunks of (h*d), coherent VECTOR loads ----
    uint4v r0[8], r1[8];
    #pragma unroll
    for (int i = 0; i < 8; ++i) {
      const int idx = i * NTHR + tid;
      const int r   = idx >> 6;          // 64 dwordx4 per row-chunk
      const int pos = idx & 63;
      const unsigned* ap = Acur + (size_t)(brow0 + r) * 512 + pos * 4;
      asm volatile("global_load_dwordx4 %0, %1, off sc0 sc1" : "=&v"(r0[i]) : "v"(ap));
    }
    asm volatile("s_waitcnt vmcnt(0)" ::: "memory");
    __builtin_amdgcn_sched_barrier(0);
    #pragma unroll
    for (int i = 0; i < 8; ++i) {
      const int idx = i * NTHR + tid;
      const int r   = idx >> 6;
      const int pos = idx & 63;
      *(uint4v*)(Axlds + r * 512 + ((pos * 8) ^ ((r & 15) << 3))) = r0[i];
    }
    #pragma unroll
    for (int i = 0; i < 8; ++i) {        // chunk1 loads in flight under chunk0 MFMA
      const int idx = i * NTHR + tid;
      const int r   = idx >> 6;
      const int pos = idx & 63;
      const unsigned* ap = Acur + (size_t)(brow0 + r) * 512 + 256 + pos * 4;
      asm volatile("global_load_dwordx4 %0, %1, off sc0 sc1" : "=&v"(r1[i]) : "v"(ap));
    }
    __syncthreads();
    hmfma(0);
    __syncthreads();                     // all waves done reading chunk0
    asm volatile("s_waitcnt vmcnt(0)" ::: "memory");
    __builtin_amdgcn_sched_barrier(0);
    #pragma unroll
    for (int i = 0; i < 8; ++i) {
      const int idx = i * NTHR + tid;
      const int r   = idx >> 6;
      const int pos = idx & 63;
      *(uint4v*)(Axlds + r * 512 + ((pos * 8) ^ ((r & 15) << 3))) = r1[i];
    }
    __syncthreads();
    hmfma(1);

    // ---- per-wave partials (C/D layout: col=lane&31, row=(r&3)+8*(r>>2)+4*(lane>>5)) ----
    {
      const int colw  = lane & 31;
      const int rbase = (lane >> 5) * 4;
      #pragma unroll
      for (int rr = 0; rr < 16; ++rr) {
        const int row = (rr & 3) + 8 * (rr >> 2) + rbase;
        gaccs[wv][row][colw] = acc[rr];
      }
    }
    __syncthreads();

    // ---- cell update: thread owns (b, j) ----
    float gv[4];
    #pragma unroll
    for (int g = 0; g < 4; ++g) {
      const int c = g * 8 + jj;
      gv[g] = gaccs[0][b_l][c] + gaccs[1][b_l][c] + gaccs[2][b_l][c] + gaccs[3][b_l][c]
            + bias_lds[c];
    }
    const float ig = sigf(gv[0]);
    const float fg = sigf(gv[1]);
    const float gg = tanhf(gv[2]);
    const float og = sigf(gv[3]);
    cstate = fg * cstate + ig * gg;
    const float h = og * tanhf(cstate);

    // publish h*d packed as u32 (even jj stores {j, j+1}) via coherent store
    {
      const unsigned hd  = f2bf(h * dval);
      const unsigned nxt = __shfl_down((int)hd, 1);
      if ((jj & 1) == 0)
        __hip_atomic_store(Anext + (size_t)b * (H_ / 2) + (j >> 1),
                           hd | (nxt << 16),
                           __ATOMIC_RELAXED, __HIP_MEMORY_SCOPE_AGENT);
    }

    asm volatile("s_waitcnt vmcnt(0)" ::: "memory");  // publish at coherent point
    __syncthreads();                                  // every wave drained

    if (t < T_ - 1 && tid == 0)
      __hip_atomic_fetch_add(mybar, 1u, __ATOMIC_RELAXED, __HIP_MEMORY_SCOPE_AGENT);

    // off the release path:
    __builtin_nontemporal_store(h, &out[((size_t)b * T_ + t) * H_ + j]);
    if (t == T_ - 1) {
      hn[(size_t)b * H_ + j] = h;
      cn[(size_t)b * H_ + j] = cstate;
    }

    if (t < T_ - 1) {        // x-projection for t+1 hides barrier latency
      xload(t + 1);
      xfin();
    }
    unsigned* tmp = Acur; Acur = Anext; Anext = tmp;
  }
}

extern "C" void kernel_launch(void* const* d_in, const int* in_sizes, int n_in,
                              void* d_out, int out_size, void* d_ws, size_t ws_size,
                              hipStream_t stream) {
  (void)in_sizes; (void)n_in; (void)out_size; (void)ws_size;
  const float* x    = (const float*)d_in[0];
  const float* img  = (const float*)d_in[1];
  const float* W_ih = (const float*)d_in[2];
  const float* W_hh = (const float*)d_in[3];
  const float* b_ih = (const float*)d_in[4];
  const float* b_hh = (const float*)d_in[5];
  const float* W_m  = (const float*)d_in[6];

  float* out = (float*)d_out;
  float* hn  = out + (size_t)B_ * T_ * H_;
  float* cn  = hn + (size_t)B_ * H_;

  unsigned* bar = (unsigned*)d_ws;
  unsigned* Ah0 = (unsigned*)((char*)d_ws + 256);
  unsigned* Ah1 = (unsigned*)((char*)d_ws + 256 + (size_t)B_ * H_ * 2);

  hipMemsetAsync(d_ws, 0, 256, stream);   // reset both barrier counters each call
  hipLaunchKernelGGL(mmlstm_persistent, dim3(NWG), dim3(NTHR), 0, stream,
                     x, img, W_ih, W_hh, b_ih, b_hh, W_m, out, hn, cn, bar, Ah0, Ah1);
}

// Round 4
// 2315.357 us; speedup vs baseline: 4.7508x; 1.0961x over previous
//
#include <hip/hip_runtime.h>
#include <math.h>

constexpr int B_   = 64;
constexpr int T_   = 512;
constexpr int D_   = 512;
constexpr int H_   = 1024;
constexpr int IMG_ = 2048;
constexpr int NWG  = 256;
constexpr int NTHR = 256;
constexpr int KTOT = D_ + H_;   // 1536

typedef __attribute__((ext_vector_type(8)))  short          short8;
typedef __attribute__((ext_vector_type(16))) float          f32x16;
typedef __attribute__((ext_vector_type(4)))  unsigned short ushort4v;
typedef __attribute__((ext_vector_type(4)))  unsigned       uint4v;

__device__ __forceinline__ unsigned short f2bf(float f) {
  unsigned u = __float_as_uint(f);
  u += 0x7FFFu + ((u >> 16) & 1u);     // round-to-nearest-even
  return (unsigned short)(u >> 16);
}

__device__ __forceinline__ float sigf(float v) {
  return 1.0f / (1.0f + __expf(-v));
}

__device__ __forceinline__ void wg_bar() {
  __builtin_amdgcn_s_barrier();
  __builtin_amdgcn_sched_barrier(0);
}

// Persistent multimodal-LSTM. Fence-free agent-scope coherence (validated R2/R3):
// publish via relaxed-atomic u32 stores (write-through to coherent point),
// consume via inline-asm global_load_dwordx4 sc0 sc1 (coalesced, L1/L2-bypass).
// NEW in v4: (a) flag-ARRAY barrier -- each WG stores its step to its own slot,
// all waves poll 128 slots in parallel; removes 128 serialized same-address
// atomic RMWs per step. (b) raw s_barrier + hand-counted vmcnt/lgkmcnt in the
// step loop; no compiler blanket vmcnt(0) drains on the critical path.
__global__ void __launch_bounds__(NTHR, 1)
mmlstm_persistent(const float* __restrict__ x,
                  const float* __restrict__ img,
                  const float* __restrict__ W_ih,
                  const float* __restrict__ W_hh,
                  const float* __restrict__ b_ih,
                  const float* __restrict__ b_hh,
                  const float* __restrict__ W_m,
                  float* __restrict__ out,
                  float* __restrict__ hn,
                  float* __restrict__ cn,
                  unsigned* __restrict__ flags,
                  unsigned* __restrict__ Ah0,
                  unsigned* __restrict__ Ah1)
{
  __shared__ unsigned short Wlds[32 * KTOT];   // 96 KiB
  __shared__ unsigned short Axlds[32 * 512];   // 32 KiB A-panel / x-tile staging
  __shared__ float gaccs[4][32][33];
  __shared__ float bias_lds[32];

  const int tid  = threadIdx.x;
  const int lane = tid & 63;
  const int wv   = tid >> 6;
  const int wg   = blockIdx.x;
  const int rgid = wg & 1;
  const int cgid = wg >> 1;
  const int brow0 = rgid * 32;
  const int j0    = cgid * 8;

  unsigned* myflags = flags + rgid * 128;   // this half's 128 slots
  unsigned* myslot  = myflags + cgid;

  // ---- stage W slice (32 gate rows = 4 gates x 8 h-cols) into LDS, bf16, swizzled ----
  for (int c = 0; c < 32; ++c) {
    const int grow = (c >> 3) * H_ + j0 + (c & 7);
    const int sw   = (c & 15) << 3;
    for (int k = tid; k < KTOT; k += NTHR) {
      const float w = (k < D_) ? W_ih[(size_t)grow * D_ + k]
                               : W_hh[(size_t)grow * H_ + (k - D_)];
      Wlds[c * KTOT + (k ^ sw)] = f2bf(w);
    }
  }
  if (tid < 32) {
    const int grow = (tid >> 3) * H_ + j0 + (tid & 7);
    bias_lds[tid] = b_ih[grow] + b_hh[grow];
  }

  const int b_l = tid >> 3;
  const int jj  = tid & 7;
  const int b   = brow0 + b_l;
  const int j   = j0 + jj;

  // multimodal gate d[b][j] = img[b] . W_m[j]
  float dval = 0.0f;
  {
    const float4* ir = (const float4*)(img + (size_t)b * IMG_);
    const float4* wr = (const float4*)(W_m + (size_t)j * IMG_);
    for (int k = 0; k < IMG_ / 4; ++k) {
      const float4 a = ir[k];
      const float4 w = wr[k];
      dval += a.x * w.x + a.y * w.y + a.z * w.z + a.w * w.w;
    }
  }

  // h0 * d = 0 : publish zeros (even-jj threads, packed u32)
  if ((tid & 1) == 0)
    __hip_atomic_store(Ah0 + (size_t)b * (H_ / 2) + (j >> 1), 0u,
                       __ATOMIC_RELAXED, __HIP_MEMORY_SCOPE_AGENT);

  float  cstate = 0.0f;
  f32x16 acc    = {};

  asm volatile("s_waitcnt vmcnt(0)" ::: "memory");
  __syncthreads();
  if (tid == 0)
    __hip_atomic_store(myslot, 1u, __ATOMIC_RELAXED, __HIP_MEMORY_SCOPE_AGENT);

  unsigned* Acur  = Ah0;
  unsigned* Anext = Ah1;

  float4 xr[16];

  auto poll = [&](unsigned target) {     // all 4 waves poll independently
    for (;;) {
      const unsigned a = __hip_atomic_load(myflags + lane,      __ATOMIC_RELAXED, __HIP_MEMORY_SCOPE_AGENT);
      const unsigned c = __hip_atomic_load(myflags + 64 + lane, __ATOMIC_RELAXED, __HIP_MEMORY_SCOPE_AGENT);
      if (__all(a >= target && c >= target)) break;
    }
  };

  auto xload = [&](int t) {
    #pragma unroll
    for (int i = 0; i < 16; ++i) {
      const int idx = i * NTHR + tid;
      const int r   = idx >> 7;
      const int pos = idx & 127;
      xr[i] = *(const float4*)(x + ((size_t)(brow0 + r) * T_ + t) * D_ + pos * 4);
    }
  };

  auto xfin = [&]() {   // pack + stage + x-projection MFMA (re-inits acc)
    #pragma unroll
    for (int i = 0; i < 16; ++i) {
      const int idx = i * NTHR + tid;
      const int r   = idx >> 7;
      const int pos = idx & 127;
      ushort4v pk;
      pk.x = f2bf(xr[i].x); pk.y = f2bf(xr[i].y);
      pk.z = f2bf(xr[i].z); pk.w = f2bf(xr[i].w);
      *(ushort4v*)(Axlds + r * 512 + ((pos * 4) ^ ((r & 15) << 3))) = pk;
    }
    asm volatile("s_waitcnt lgkmcnt(0)" ::: "memory");
    wg_bar();
    acc = {};
    const int r  = lane & 31;
    const int kh = (lane >> 5) << 3;
    #pragma unroll
    for (int s8 = 0; s8 < 8; ++s8) {
      const int kl = (wv + s8 * 4) * 16 + kh;
      const short8 af = *(const short8*)(Axlds + r * 512  + (kl ^ ((r & 15) << 3)));
      const short8 bf = *(const short8*)(Wlds  + r * KTOT + (kl ^ ((r & 15) << 3)));
      acc = __builtin_amdgcn_mfma_f32_32x32x16_bf16(af, bf, acc, 0, 0, 0);
    }
  };

  auto hmfma = [&](int hc) {
    const int r  = lane & 31;
    const int kh = (lane >> 5) << 3;
    #pragma unroll
    for (int s8 = 0; s8 < 8; ++s8) {
      const int kloc = (wv + s8 * 4) * 16 + kh;
      const int kglb = D_ + hc * 512 + kloc;
      const short8 af = *(const short8*)(Axlds + r * 512  + (kloc ^ ((r & 15) << 3)));
      const short8 bf = *(const short8*)(Wlds  + r * KTOT + (kglb ^ ((r & 15) << 3)));
      acc = __builtin_amdgcn_mfma_f32_32x32x16_bf16(af, bf, acc, 0, 0, 0);
    }
  };

  xload(0);
  xfin();

  for (int t = 0; t < T_; ++t) {
    wg_bar();          // all waves done with Axlds (x-tile) before panel writes
    poll((unsigned)(t + 1));

    // ---- issue all 16 coherent panel loads (2 chunks x 8 dwordx4) ----
    uint4v r0[8], r1[8];
    #pragma unroll
    for (int i = 0; i < 8; ++i) {
      const int idx = i * NTHR + tid;
      const int r   = idx >> 6;
      const int pos = idx & 63;
      const unsigned* ap = Acur + (size_t)(brow0 + r) * 512 + pos * 4;
      asm volatile("global_load_dwordx4 %0, %1, off sc0 sc1" : "=&v"(r0[i]) : "v"(ap));
    }
    #pragma unroll
    for (int i = 0; i < 8; ++i) {
      const int idx = i * NTHR + tid;
      const int r   = idx >> 6;
      const int pos = idx & 63;
      const unsigned* ap = Acur + (size_t)(brow0 + r) * 512 + 256 + pos * 4;
      asm volatile("global_load_dwordx4 %0, %1, off sc0 sc1" : "=&v"(r1[i]) : "v"(ap));
    }

    asm volatile("s_waitcnt vmcnt(8)" ::: "memory");   // chunk0 arrived
    __builtin_amdgcn_sched_barrier(0);
    #pragma unroll
    for (int i = 0; i < 8; ++i) {
      const int idx = i * NTHR + tid;
      const int r   = idx >> 6;
      const int pos = idx & 63;
      *(uint4v*)(Axlds + r * 512 + ((pos * 8) ^ ((r & 15) << 3))) = r0[i];
    }
    asm volatile("s_waitcnt lgkmcnt(0)" ::: "memory");
    wg_bar();
    hmfma(0);
    wg_bar();          // all waves' chunk0 ds_reads done

    asm volatile("s_waitcnt vmcnt(0)" ::: "memory");   // chunk1 arrived
    __builtin_amdgcn_sched_barrier(0);
    #pragma unroll
    for (int i = 0; i < 8; ++i) {
      const int idx = i * NTHR + tid;
      const int r   = idx >> 6;
      const int pos = idx & 63;
      *(uint4v*)(Axlds + r * 512 + ((pos * 8) ^ ((r & 15) << 3))) = r1[i];
    }
    asm volatile("s_waitcnt lgkmcnt(0)" ::: "memory");
    wg_bar();
    hmfma(1);

    // ---- per-wave partials (C/D: col=lane&31, row=(rr&3)+8*(rr>>2)+4*(lane>>5)) ----
    {
      const int colw  = lane & 31;
      const int rbase = (lane >> 5) * 4;
      #pragma unroll
      for (int rr = 0; rr < 16; ++rr) {
        const int row = (rr & 3) + 8 * (rr >> 2) + rbase;
        gaccs[wv][row][colw] = acc[rr];
      }
    }
    asm volatile("s_waitcnt lgkmcnt(0)" ::: "memory");
    wg_bar();

    // ---- cell update ----
    float gv[4];
    #pragma unroll
    for (int g = 0; g < 4; ++g) {
      const int c = g * 8 + jj;
      gv[g] = gaccs[0][b_l][c] + gaccs[1][b_l][c] + gaccs[2][b_l][c] + gaccs[3][b_l][c]
            + bias_lds[c];
    }
    const float ig = sigf(gv[0]);
    const float fg = sigf(gv[1]);
    const float gg = tanhf(gv[2]);
    const float og = sigf(gv[3]);
    cstate = fg * cstate + ig * gg;
    const float h = og * tanhf(cstate);

    // publish h*d packed as u32 (even jj stores {j, j+1})
    {
      const unsigned hd  = f2bf(h * dval);
      const unsigned nxt = __shfl_down((int)hd, 1);
      if ((jj & 1) == 0)
        __hip_atomic_store(Anext + (size_t)b * (H_ / 2) + (j >> 1),
                           hd | (nxt << 16),
                           __ATOMIC_RELAXED, __HIP_MEMORY_SCOPE_AGENT);
    }
    asm volatile("s_waitcnt vmcnt(0)" ::: "memory");   // publishes at coherent point
    wg_bar();                                          // every wave drained
    if (t < T_ - 1 && tid == 0)
      __hip_atomic_store(myslot, (unsigned)(t + 2), __ATOMIC_RELAXED, __HIP_MEMORY_SCOPE_AGENT);

    // off the release path:
    __builtin_nontemporal_store(h, &out[((size_t)b * T_ + t) * H_ + j]);
    if (t == T_ - 1) {
      hn[(size_t)b * H_ + j] = h;
      cn[(size_t)b * H_ + j] = cstate;
    }
    if (t < T_ - 1) {
      xload(t + 1);
      xfin();
    }
    unsigned* tmp = Acur; Acur = Anext; Anext = tmp;
  }
}

extern "C" void kernel_launch(void* const* d_in, const int* in_sizes, int n_in,
                              void* d_out, int out_size, void* d_ws, size_t ws_size,
                              hipStream_t stream) {
  (void)in_sizes; (void)n_in; (void)out_size; (void)ws_size;
  const float* x    = (const float*)d_in[0];
  const float* img  = (const float*)d_in[1];
  const float* W_ih = (const float*)d_in[2];
  const float* W_hh = (const float*)d_in[3];
  const float* b_ih = (const float*)d_in[4];
  const float* b_hh = (const float*)d_in[5];
  const float* W_m  = (const float*)d_in[6];

  float* out = (float*)d_out;
  float* hn  = out + (size_t)B_ * T_ * H_;
  float* cn  = hn + (size_t)B_ * H_;

  unsigned* flags = (unsigned*)d_ws;                                   // 256 slots
  unsigned* Ah0   = (unsigned*)((char*)d_ws + 4096);
  unsigned* Ah1   = (unsigned*)((char*)d_ws + 4096 + (size_t)B_ * H_ * 2);

  hipMemsetAsync(d_ws, 0, 4096, stream);   // reset flag array each call
  hipLaunchKernelGGL(mmlstm_persistent, dim3(NWG), dim3(NTHR), 0, stream,
                     x, img, W_ih, W_hh, b_ih, b_hh, W_m, out, hn, cn, flags, Ah0, Ah1);
}